// Round 6
// baseline (101.307 us; speedup 1.0000x reference)
//
#include <hip/hip_runtime.h>
#include <math.h>

// Attention fwd: Q[N,64] K[N,64] V[N,64] fp32 -> O[N,64] fp32
// R5: R4 (dbuf + counted vmcnt) with:
//  - Q conversion folded into main kernel prologue (no Qb in ws)
//  - prepass does only K-cast + V^T (smaller grid)
//  - s_setprio(1) around MFMA clusters (T5; dbuf gives waves role diversity)
//  - 16-way key split, partials in d_ws, combine kernel. Exp2-domain softmax,
//    defer-max THR=10, XOR-swizzled LDS, global_load_lds staging.

typedef __bf16 bf16;
typedef __attribute__((ext_vector_type(4)))  __bf16 bf16x4;
typedef __attribute__((ext_vector_type(8)))  __bf16 bf16x8;
typedef __attribute__((ext_vector_type(16))) float  f32x16;

#define DKc 64
#define DVc 64
#define TK  64
#define QW  32
#define NW  4
#define QB  (QW * NW)   // 128 queries per block
#define SCALE_LOG2E 0.1803368801111204f   // 0.125 * log2(e)

__device__ __forceinline__ f32x16 mfma_bf16(bf16x8 a, bf16x8 b, f32x16 c) {
    return __builtin_amdgcn_mfma_f32_32x32x16_bf16(a, b, c, 0, 0, 0);
}
__device__ __forceinline__ int rp4(int r) {   // PV k-slot permute (involution)
    return ((r >> 2) & 1) * 8 + (r & 3) + ((r >> 3) << 2);
}

// ---------------- prepass: Kb = bf16(K); Vt = bf16 V^T (slot-permuted) ------
__global__ __launch_bounds__(256)
void prepass(const float* __restrict__ K, const float* __restrict__ V,
             bf16* __restrict__ Kb, bf16* __restrict__ Vt, int N) {
    const int b = blockIdx.x, tid = threadIdx.x;
    const int nkb = (N * DKc) / (256 * 4);          // float4 blocks for K
    if (b < nkb) {
        int idx = b * 256 + tid;
        float4 v = ((const float4*)K)[idx];
        bf16x4 w;
        w[0] = (bf16)v.x; w[1] = (bf16)v.y; w[2] = (bf16)v.z; w[3] = (bf16)v.w;
        ((bf16x4*)Kb)[idx] = w;
    } else {
        // V transpose tile: 64 keys x 64 dv -> Vt[dv][T*64 + permuted key]
        const int T = b - nkb;
        __shared__ float sT[64][65];
#pragma unroll
        for (int p = 0; p < 4; ++p) {
            int fi = p * 256 + tid;                 // float4 index in tile
            int e0 = fi * 4;
            int key = e0 >> 6, dv = e0 & 63;
            float4 v = ((const float4*)(V + (size_t)T * 64 * DVc))[fi];
            sT[dv + 0][key] = v.x; sT[dv + 1][key] = v.y;
            sT[dv + 2][key] = v.z; sT[dv + 3][key] = v.w;
        }
        __syncthreads();
#pragma unroll
        for (int w = 0; w < 2; ++w) {
            int vidx = w * 256 + tid;
            int dv = vidx >> 3, j0 = (vidx & 7) * 8;
            bf16x8 o;
#pragma unroll
            for (int i = 0; i < 8; ++i) {
                int j = j0 + i;
                int ks = (j & 48) | rp4(j & 15);
                o[i] = (bf16)sT[dv][ks];
            }
            *(bf16x8*)(Vt + (size_t)dv * N + T * 64 + j0) = o;
        }
    }
}

// ---------------- main flash kernel ----------------------------------------
__global__ __launch_bounds__(256, 4)
void attn_fwd_mfma(const float* __restrict__ Q, const bf16* __restrict__ Kb,
                   const bf16* __restrict__ Vt,
                   float* __restrict__ Opart, float* __restrict__ Mpart,
                   float* __restrict__ Lpart, float* __restrict__ Out,
                   int N, int splits, int chunk) {
    // double-buffered tiles, 8 KB each: [key][dk] / [dv][key'], swizzled
    __shared__ __align__(16) short sK[2][TK * DKc];
    __shared__ __align__(16) short sV[2][DVc * TK];

    const int tid  = threadIdx.x;
    const int wid  = tid >> 6;
    const int lane = tid & 63;
    const int l31  = lane & 31;
    const int h    = lane >> 5;

    const int qbase = blockIdx.x * QB + wid * QW;
    const int q     = qbase + l31;
    const int sp    = blockIdx.y;

    // Q fragments from fp32 (folded prepass): qf[f][j] = Q[q][f*16+h*8+j]*s
    bf16x8 qf[4];
#pragma unroll
    for (int f = 0; f < 4; ++f) {
        const float* qp = Q + (size_t)q * DKc + f * 16 + h * 8;
        float4 a = *(const float4*)qp;
        float4 b = *(const float4*)(qp + 4);
        qf[f][0] = (bf16)(a.x * SCALE_LOG2E); qf[f][1] = (bf16)(a.y * SCALE_LOG2E);
        qf[f][2] = (bf16)(a.z * SCALE_LOG2E); qf[f][3] = (bf16)(a.w * SCALE_LOG2E);
        qf[f][4] = (bf16)(b.x * SCALE_LOG2E); qf[f][5] = (bf16)(b.y * SCALE_LOG2E);
        qf[f][6] = (bf16)(b.z * SCALE_LOG2E); qf[f][7] = (bf16)(b.w * SCALE_LOG2E);
    }

    f32x16 O0 = {0}, O1 = {0};
    float m = -1e30f, lsum = 0.f;

    const int k0 = sp * chunk;
    int k1 = k0 + chunk; if (k1 > N) k1 = N;
    const int ntiles = (k1 - k0) / TK;

    const char* KbB = (const char*)Kb;
    const char* VtB = (const char*)Vt;
    const size_t vrow = (size_t)N * 2;             // Vt row stride in bytes

    // issue one tile's staging loads (4 global_load_lds / thread)
    auto stage = [&](int buf, int t0) {
        char* sKb = (char*)&sK[buf][0];
        char* sVb = (char*)&sV[buf][0];
#pragma unroll
        for (int p = 0; p < 2; ++p) {
            int o   = p * 4096 + wid * 1024 + lane * 16;
            int key = o >> 7;
            int so  = o ^ ((key & 7) << 4);
            __builtin_amdgcn_global_load_lds(
                (const __attribute__((address_space(1))) void*)(KbB + (size_t)t0 * 128 + so),
                (__attribute__((address_space(3))) void*)(sKb + p * 4096 + wid * 1024),
                16, 0, 0);
        }
#pragma unroll
        for (int p = 0; p < 2; ++p) {
            int o  = p * 4096 + wid * 1024 + lane * 16;
            int dv = o >> 7;
            int kb = o & 127;
            int so = kb ^ ((dv & 7) << 4);
            __builtin_amdgcn_global_load_lds(
                (const __attribute__((address_space(1))) void*)(VtB + (size_t)dv * vrow + (size_t)t0 * 2 + so),
                (__attribute__((address_space(3))) void*)(sVb + p * 4096 + wid * 1024),
                16, 0, 0);
        }
    };

    stage(0, k0);
    int cur = 0;

    for (int it = 0; it < ntiles; ++it) {
        if (it + 1 < ntiles) {
            stage(cur ^ 1, k0 + (it + 1) * TK);
            // wait only the 4 OLDEST vmem ops = current tile's loads
            asm volatile("s_waitcnt vmcnt(4)" ::: "memory");
        } else {
            asm volatile("s_waitcnt vmcnt(0)" ::: "memory");
        }
        __builtin_amdgcn_sched_barrier(0);
        __builtin_amdgcn_s_barrier();

        const char* sKc = (const char*)&sK[cur][0];
        const char* sVc = (const char*)&sV[cur][0];

        // ---- QK^T: D[key, q]
        f32x16 d0 = {0}, d1 = {0};
        __builtin_amdgcn_s_setprio(1);
#pragma unroll
        for (int f = 0; f < 4; ++f) {
            int keyA = l31, keyB = 32 + l31;
            int ba = ((keyA * 128) + f * 32 + h * 16) ^ ((keyA & 7) << 4);
            int bb = ((keyB * 128) + f * 32 + h * 16) ^ ((keyB & 7) << 4);
            bf16x8 kf0 = *(const bf16x8*)(sKc + ba);
            bf16x8 kf1 = *(const bf16x8*)(sKc + bb);
            d0 = mfma_bf16(kf0, qf[f], d0);
            d1 = mfma_bf16(kf1, qf[f], d1);
        }
        __builtin_amdgcn_s_setprio(0);

        // ---- online softmax, exp2 domain, defer-max (THR=10)
        float tm = -1e30f;
#pragma unroll
        for (int r = 0; r < 16; ++r) tm = fmaxf(tm, fmaxf(d0[r], d1[r]));
        tm = fmaxf(tm, __shfl_xor(tm, 32));

        float fs = 1.f;
        if (__any(tm > m + 10.f)) {
            float mn = fmaxf(m, tm);
            fs = __builtin_amdgcn_exp2f(m - mn);   // first tile: -> 0
            m = mn;
#pragma unroll
            for (int r = 0; r < 16; ++r) {
                int qr = (r & 3) + 8 * (r >> 2) + 4 * h;
                float fr = __shfl(fs, (lane & 32) | qr);
                O0[r] *= fr; O1[r] *= fr;
            }
        }

        float psum = 0.f;
#pragma unroll
        for (int r = 0; r < 16; ++r) {
            d0[r] = __builtin_amdgcn_exp2f(d0[r] - m); psum += d0[r];
            d1[r] = __builtin_amdgcn_exp2f(d1[r] - m); psum += d1[r];
        }
        psum += __shfl_xor(psum, 32);
        lsum = lsum * fs + psum;

        // ---- pack P -> A frags
        bf16x8 pa[4];
#pragma unroll
        for (int j = 0; j < 8; ++j) {
            pa[0][j] = (bf16)d0[j];
            pa[1][j] = (bf16)d0[8 + j];
            pa[2][j] = (bf16)d1[j];
            pa[3][j] = (bf16)d1[8 + j];
        }

        // ---- PV
        __builtin_amdgcn_s_setprio(1);
#pragma unroll
        for (int kb = 0; kb < 4; ++kb) {
            int dvA = l31, dvB = 32 + l31;
            int ba = ((dvA * 128) + kb * 32 + h * 16) ^ ((dvA & 7) << 4);
            int bb = ((dvB * 128) + kb * 32 + h * 16) ^ ((dvB & 7) << 4);
            bf16x8 vf0 = *(const bf16x8*)(sVc + ba);
            bf16x8 vf1 = *(const bf16x8*)(sVc + bb);
            O0 = mfma_bf16(pa[kb], vf0, O0);
            O1 = mfma_bf16(pa[kb], vf1, O1);
        }
        __builtin_amdgcn_s_setprio(0);

        __builtin_amdgcn_s_barrier();   // all waves done reading buf[cur]
        cur ^= 1;
    }

    // ---- epilogue
    if (splits == 1) {
        float inv = 1.f / lsum;
#pragma unroll
        for (int r = 0; r < 16; ++r) {
            int qr = (r & 3) + 8 * (r >> 2) + 4 * h;
            float fr = __shfl(inv, (lane & 32) | qr);
            int qq = qbase + qr;
            Out[(size_t)qq * DVc + l31]      = O0[r] * fr;
            Out[(size_t)qq * DVc + 32 + l31] = O1[r] * fr;
        }
    } else {
#pragma unroll
        for (int r = 0; r < 16; ++r) {
            int qr = (r & 3) + 8 * (r >> 2) + 4 * h;
            int qq = qbase + qr;
            size_t off = ((size_t)sp * N + qq) * DVc;
            Opart[off + l31]      = O0[r];
            Opart[off + 32 + l31] = O1[r];
        }
        if (lane < 32) {
            Mpart[(size_t)sp * N + q] = m;
            Lpart[(size_t)sp * N + q] = lsum;
        }
    }
}

// ---------------- combine (exp2 domain) ------------------------------------
__global__ __launch_bounds__(256)
void attn_combine(const float* __restrict__ Opart, const float* __restrict__ Mpart,
                  const float* __restrict__ Lpart, float* __restrict__ Out,
                  int N, int splits) {
    const int t  = blockIdx.x * blockDim.x + threadIdx.x;
    const int q  = t >> 4;
    const int d4 = t & 15;

    float M = -1e30f;
    for (int s = 0; s < splits; ++s) M = fmaxf(M, Mpart[(size_t)s * N + q]);

    float4 acc = make_float4(0.f, 0.f, 0.f, 0.f);
    float  L = 0.f;
    for (int s = 0; s < splits; ++s) {
        float w = __builtin_amdgcn_exp2f(Mpart[(size_t)s * N + q] - M);
        L += w * Lpart[(size_t)s * N + q];
        float4 ov = *(const float4*)(Opart + ((size_t)s * N + q) * DVc + d4 * 4);
        acc.x += w * ov.x; acc.y += w * ov.y; acc.z += w * ov.z; acc.w += w * ov.w;
    }
    float inv = 1.f / L;
    *(float4*)(Out + (size_t)q * DVc + d4 * 4) =
        make_float4(acc.x * inv, acc.y * inv, acc.z * inv, acc.w * inv);
}

extern "C" void kernel_launch(void* const* d_in, const int* in_sizes, int n_in,
                              void* d_out, int out_size, void* d_ws, size_t ws_size,
                              hipStream_t stream) {
    const float* Q = (const float*)d_in[0];
    const float* K = (const float*)d_in[1];
    const float* V = (const float*)d_in[2];
    float* Out = (float*)d_out;

    const int N = in_sizes[0] / DKc;   // 8192

    // ws layout: Kb | Vt (bf16, N*64 each) | Opart | Mpart | Lpart
    const size_t bfbytes = (size_t)N * DKc * sizeof(short);
    bf16* Kb = (bf16*)d_ws;
    bf16* Vt = (bf16*)((char*)d_ws + bfbytes);
    char* rest = (char*)d_ws + 2 * bfbytes;
    size_t rest_sz = (ws_size > 2 * bfbytes) ? ws_size - 2 * bfbytes : 0;

    int splits = 16;
    while (splits > 1 &&
           (size_t)splits * (size_t)N * (DVc + 2) * sizeof(float) > rest_sz)
        splits >>= 1;
    int chunk = (N + splits - 1) / splits;
    chunk = ((chunk + TK - 1) / TK) * TK;

    float* Opart = (float*)rest;
    float* Mpart = Opart + (size_t)splits * N * DVc;
    float* Lpart = Mpart + (size_t)splits * N;

    const int nkb = (N * DKc) / (256 * 4);
    prepass<<<nkb + N / TK, 256, 0, stream>>>(K, V, Kb, Vt, N);

    dim3 grid(N / QB, splits);
    attn_fwd_mfma<<<grid, 256, 0, stream>>>(Q, Kb, Vt, Opart, Mpart, Lpart, Out,
                                            N, splits, chunk);
    if (splits > 1) {
        int total = N * 16;
        attn_combine<<<total / 256, 256, 0, stream>>>(Opart, Mpart, Lpart, Out,
                                                      N, splits);
    }
}